// Round 10
// baseline (315.723 us; speedup 1.0000x reference)
//
#include <hip/hip_runtime.h>

#define BB 32
#define TT 1024
#define ENCD 1024
#define DECD 1024
#define MELD 80
#define KTOT (MELD + ENCD + DECD)   // 2128
#define NZ (4 * DECD)               // 4096
#define KCH 64                      // k-rows per zmm chunk
#define KC 34                       // ceil(2128/64); last chunk = 16 rows
#define NP 128                      // attn partials per batch: 32 tt x 4 waves

// ---- static device scratch ----
__device__ float g_pctx[BB * NP * ENCD];   // attn context partials (16 MB)
__device__ float g_pm[BB * NP];
__device__ float g_ps[BB * NP];
__device__ float g_ctx[BB * ENCD];
__device__ float g_zp[KC * BB * NZ];       // z partials [kc][b][j] (17.8 MB)
__device__ float g_hn[BB * DECD];

__device__ __forceinline__ float tanh_fast(float x) {
    // 1 - 2/(e+1): exact +-1 limits (rcp(inf)=0)
    return 1.f - __fdividef(2.f, __expf(2.f * x) + 1.f);
}
__device__ __forceinline__ float sigmoid_fast(float x) {
    return __fdividef(1.f, 1.f + __expf(-x));
}

// ---------------------------------------------------------------------------
// K1: fused scores + online-softmax + context partials. ONE pass over enc.
// grid (b=32, tt=32), 256 threads = 4 waves; each wave owns 8 t-rows.
// Per row: load row into regs (4x float4/lane), score via fma + butterfly
// shuffle (no LDS/syncs), fold into online (m, s, ctx[16]/lane) accumulator.
// Wave partials -> g_pctx/g_pm/g_ps.
// ---------------------------------------------------------------------------
__global__ __launch_bounds__(256) void k_attn(const float* __restrict__ enc,
                                              const float* __restrict__ h,
                                              const float* __restrict__ scale) {
    int b = blockIdx.x, tt = blockIdx.y;
    int tid = threadIdx.x, w = tid >> 6, lane = tid & 63;
    const float4* hp = (const float4*)(h + (size_t)b * DECD);
    const float4* sp = (const float4*)scale;
    float4 hv[4], sv[4];
#pragma unroll
    for (int j = 0; j < 4; j++) { hv[j] = hp[lane + j * 64]; sv[j] = sp[lane + j * 64]; }

    float m = -1e30f, s = 0.f;
    float4 cx[4];
#pragma unroll
    for (int j = 0; j < 4; j++) { cx[j].x = cx[j].y = cx[j].z = cx[j].w = 0.f; }

    int t0 = tt * 32 + w * 8;
    for (int r = 0; r < 8; r++) {
        const float4* rp = (const float4*)(enc + ((size_t)b * TT + t0 + r) * ENCD);
        float4 e[4];
#pragma unroll
        for (int j = 0; j < 4; j++) e[j] = rp[lane + j * 64];
        float p = 0.f;
#pragma unroll
        for (int j = 0; j < 4; j++) {
            p += sv[j].x * tanh_fast(hv[j].x + e[j].x);
            p += sv[j].y * tanh_fast(hv[j].y + e[j].y);
            p += sv[j].z * tanh_fast(hv[j].z + e[j].z);
            p += sv[j].w * tanh_fast(hv[j].w + e[j].w);
        }
#pragma unroll
        for (int off = 1; off < 64; off <<= 1) p += __shfl_xor(p, off, 64);
        float mn = fmaxf(m, p);
        float al = __expf(m - mn);
        float wt = __expf(p - mn);
        s = s * al + wt;
#pragma unroll
        for (int j = 0; j < 4; j++) {
            cx[j].x = cx[j].x * al + wt * e[j].x;
            cx[j].y = cx[j].y * al + wt * e[j].y;
            cx[j].z = cx[j].z * al + wt * e[j].z;
            cx[j].w = cx[j].w * al + wt * e[j].w;
        }
        m = mn;
    }
    int pidx = (b * 32 + tt) * 4 + w;
    float4* pc = (float4*)g_pctx + (size_t)pidx * (ENCD / 4);
#pragma unroll
    for (int j = 0; j < 4; j++) pc[lane + j * 64] = cx[j];
    if (lane == 0) { g_pm[pidx] = m; g_ps[pidx] = s; }
}

// ---------------------------------------------------------------------------
// K2: combine attn partials -> ctx[b,d].
// grid (b=32, dq=4), 256 threads; coalesced partial reads (16 MB total).
// ---------------------------------------------------------------------------
__global__ __launch_bounds__(256) void k_combine() {
    int b = blockIdx.x, dq = blockIdx.y, tid = threadIdx.x;
    __shared__ float lm[NP], ls[NP], em[NP];
    if (tid < NP) { lm[tid] = g_pm[b * NP + tid]; ls[tid] = g_ps[b * NP + tid]; }
    __syncthreads();
    float mg = -1e30f;
#pragma unroll 8
    for (int p = 0; p < NP; p++) mg = fmaxf(mg, lm[p]);
    float sg = 0.f;
#pragma unroll 8
    for (int p = 0; p < NP; p++) sg += ls[p] * __expf(lm[p] - mg);
    if (tid < NP) em[tid] = __expf(lm[tid] - mg);
    __syncthreads();
    int d = dq * 256 + tid;
    float acc = 0.f;
#pragma unroll 4
    for (int p = 0; p < NP; p++)
        acc = fmaf(g_pctx[((size_t)(b * NP + p)) * ENCD + d], em[p], acc);
    g_ctx[b * ENCD + d] = __fdividef(acc, sg);
}

// ---------------------------------------------------------------------------
// K3: z partials. grid 544 = 16 jt x 34 kc (KCH=64; last chunk 16 rows).
// x staged in LDS for all 32 batches; weight loads batched 8-wide.
// ---------------------------------------------------------------------------
__global__ __launch_bounds__(256) void k_zmm(const float* __restrict__ pm,
                                             const float* __restrict__ h,
                                             const float* __restrict__ kern,
                                             const float* __restrict__ reck) {
    __shared__ float xs[KCH * 32];
    int jt = blockIdx.x & 15, kc = blockIdx.x >> 4;
    int k0 = kc * KCH;
    int kcount = min(KCH, KTOT - k0);   // 64 or 16, both divisible by 8
    int tid = threadIdx.x;
    for (int idx = tid; idx < kcount * 32; idx += 256) {
        int kk = idx >> 5, b = idx & 31;
        int k = k0 + kk;
        float v;
        if (k < MELD)             v = pm[b * MELD + k];
        else if (k < MELD + ENCD) v = g_ctx[b * ENCD + (k - MELD)];
        else                      v = h[b * DECD + (k - MELD - ENCD)];
        xs[idx] = v;
    }
    __syncthreads();
    int j = jt * 256 + tid;
    float acc[32];
#pragma unroll
    for (int b = 0; b < 32; b++) acc[b] = 0.f;
    for (int kk0 = 0; kk0 < kcount; kk0 += 8) {
        float w[8];
#pragma unroll
        for (int i = 0; i < 8; i++) {
            int k = k0 + kk0 + i;
            w[i] = (k < MELD + ENCD) ? kern[(size_t)k * NZ + j]
                                     : reck[(size_t)(k - MELD - ENCD) * NZ + j];
        }
#pragma unroll
        for (int i = 0; i < 8; i++) {
            const float* xr = xs + (kk0 + i) * 32;
#pragma unroll
            for (int b = 0; b < 32; b++) acc[b] = fmaf(xr[b], w[i], acc[b]);
        }
    }
#pragma unroll
    for (int b = 0; b < 32; b++) g_zp[((size_t)kc * BB + b) * NZ + j] = acc[b];
}

// ---------------------------------------------------------------------------
// K4: sum z partials + bias, gates -> h_new/c_new (fp32 out).
// grid 128 = 32 b x 4 jq. out: mel[0,2560) h[2560,35328) c[35328,68096)
// ---------------------------------------------------------------------------
__global__ __launch_bounds__(256) void k_gates(const float* __restrict__ bias,
                                               const float* __restrict__ c,
                                               float* __restrict__ out) {
    int b = blockIdx.x >> 2, jq = blockIdx.x & 3;
    int j = jq * 256 + threadIdx.x;
    float zi = bias[j], zf = bias[1024 + j], zg = bias[2048 + j], zo = bias[3072 + j];
#pragma unroll 4
    for (int kc = 0; kc < KC; kc++) {
        const float* zp = g_zp + ((size_t)kc * BB + b) * NZ;
        zi += zp[j];
        zf += zp[1024 + j];
        zg += zp[2048 + j];
        zo += zp[3072 + j];
    }
    int idx = b * 1024 + j;
    float cn = sigmoid_fast(zf) * c[idx] + sigmoid_fast(zi) * tanh_fast(zg);
    float hn = sigmoid_fast(zo) * tanh_fast(cn);
    g_hn[idx] = hn;
    out[2560 + idx] = hn;
    out[35328 + idx] = cn;
}

// ---------------------------------------------------------------------------
// K5: mel[b,m] = h_new[b,:] @ proj_w[:,m] + proj_b[m]
// grid 32; 160 active threads = 80 m x 2 d-halves, LDS combine.
// ---------------------------------------------------------------------------
__global__ __launch_bounds__(256) void k_proj(const float* __restrict__ pw,
                                              const float* __restrict__ pb,
                                              float* __restrict__ out) {
    __shared__ float lh[1024];
    __shared__ float pacc[2][MELD];
    int b = blockIdx.x, tid = threadIdx.x;
    for (int i = tid; i < 1024; i += 256) lh[i] = g_hn[b * 1024 + i];
    __syncthreads();
    int m = tid & 127;
    int g = tid >> 7;
    if (m < MELD) {
        float acc = 0.f;
        int d0 = g * 512;
#pragma unroll 8
        for (int d = d0; d < d0 + 512; d++) acc = fmaf(lh[d], pw[d * MELD + m], acc);
        pacc[g][m] = acc;
    }
    __syncthreads();
    if (tid < MELD) out[b * MELD + tid] = pacc[0][tid] + pacc[1][tid] + pb[tid];
}

extern "C" void kernel_launch(void* const* d_in, const int* in_sizes, int n_in,
                              void* d_out, int out_size, void* d_ws, size_t ws_size,
                              hipStream_t stream) {
    const float* pm   = (const float*)d_in[0];   // prev_mel_frame [32,80]
    const float* enc  = (const float*)d_in[1];   // encoder_outputs [32,1024,1024]
    const float* h    = (const float*)d_in[2];   // h [32,1024]
    const float* c    = (const float*)d_in[3];   // c [32,1024]
    const float* asc  = (const float*)d_in[4];   // attn_scale [1024]
    const float* kern = (const float*)d_in[5];   // kernel [1104,4096]
    const float* reck = (const float*)d_in[6];   // rec_kernel [1024,4096]
    const float* bias = (const float*)d_in[7];   // bias [4096]
    const float* pw   = (const float*)d_in[8];   // proj_w [1024,80]
    const float* pb   = (const float*)d_in[9];   // proj_b [80]
    float* out = (float*)d_out;                  // fp32: mel | h_new | c_new

    k_attn   <<<dim3(32, 32), 256, 0, stream>>>(enc, h, asc);
    k_combine<<<dim3(32, 4), 256, 0, stream>>>();
    k_zmm    <<<544, 256, 0, stream>>>(pm, h, kern, reck);
    k_gates  <<<128, 256, 0, stream>>>(bias, c, out);
    k_proj   <<<32, 256, 0, stream>>>(pw, pb, out);
}

// Round 11
// 300.638 us; speedup vs baseline: 1.0502x; 1.0502x over previous
//
#include <hip/hip_runtime.h>

#define BB 32
#define TT 1024
#define ENCD 1024
#define DECD 1024
#define MELD 80
#define KTOT (MELD + ENCD + DECD)   // 2128
#define NZ (4 * DECD)               // 4096
#define KCH 64                      // k-rows per zmm chunk
#define KC 34                       // ceil(2128/64); last chunk = 16 rows
#define NTT 32                      // context t-tiles (32 rows each)

// ---- static device scratch ----
__device__ float g_scores[BB * TT];
__device__ float g_cp[NTT * BB * ENCD];  // context partials [tt][b][d] (4 MB)
__device__ float g_ctx[BB * ENCD];
__device__ float g_zp[KC * BB * NZ];     // z partials [kc][b][j] (17.8 MB)
__device__ float g_hn[BB * DECD];

__device__ __forceinline__ float tanh_fast(float x) {
    // 1 - 2/(e+1): exact +-1 limits (rcp(inf)=0)
    return 1.f - __fdividef(2.f, __expf(2.f * x) + 1.f);
}
__device__ __forceinline__ float sigmoid_fast(float x) {
    return __fdividef(1.f, 1.f + __expf(-x));
}

// ---------------------------------------------------------------------------
// K1: scores[b,t] = sum_d scale[d] * tanh(h[b,d] + enc[b,t,d])
// one wave per (b,t); float4 loads, lanes contiguous (1KB/wave-instr).
// ---------------------------------------------------------------------------
__global__ __launch_bounds__(256) void k_scores(const float* __restrict__ enc,
                                                const float* __restrict__ h,
                                                const float* __restrict__ scale) {
    int w = blockIdx.x * 4 + (threadIdx.x >> 6);   // b*1024 + t
    int lane = threadIdx.x & 63;
    int b = w >> 10;
    const float4* ep = (const float4*)(enc + (size_t)w * ENCD);
    const float4* hp = (const float4*)(h + (size_t)b * DECD);
    const float4* sp = (const float4*)scale;
    float sum = 0.f;
#pragma unroll
    for (int j = 0; j < 4; j++) {
        int i = lane + j * 64;
        float4 e = ep[i], hv = hp[i], s = sp[i];
        sum += s.x * tanh_fast(hv.x + e.x);
        sum += s.y * tanh_fast(hv.y + e.y);
        sum += s.z * tanh_fast(hv.z + e.z);
        sum += s.w * tanh_fast(hv.w + e.w);
    }
#pragma unroll
    for (int off = 32; off > 0; off >>= 1) sum += __shfl_down(sum, off, 64);
    if (lane == 0) g_scores[w] = sum;
}

// ---------------------------------------------------------------------------
// K2: fused softmax + context partials.
// grid (b=32, tt=32) = 1024 blocks (4/CU), 256 threads. Block re-derives
// (m,s) from scores[b,:] (L2-hot, deterministic), builds its 32-t attn tile
// in LDS, accumulates ctx partial for all 1024 d (float4/thread) over 32
// independent row loads, writes g_cp[tt][b][:].
// ---------------------------------------------------------------------------
__global__ __launch_bounds__(256) void k_context(const float* __restrict__ enc) {
    int b = blockIdx.x, tt = blockIdx.y, tid = threadIdx.x;
    __shared__ float red[4];
    __shared__ float la[32];
    float v[4];
#pragma unroll
    for (int i = 0; i < 4; i++) v[i] = g_scores[b * TT + tid + i * 256];
    float m = fmaxf(fmaxf(v[0], v[1]), fmaxf(v[2], v[3]));
#pragma unroll
    for (int off = 32; off > 0; off >>= 1) m = fmaxf(m, __shfl_down(m, off, 64));
    if ((tid & 63) == 0) red[tid >> 6] = m;
    __syncthreads();
    m = fmaxf(fmaxf(red[0], red[1]), fmaxf(red[2], red[3]));
    __syncthreads();
    float s = 0.f;
#pragma unroll
    for (int i = 0; i < 4; i++) s += __expf(v[i] - m);
#pragma unroll
    for (int off = 32; off > 0; off >>= 1) s += __shfl_down(s, off, 64);
    if ((tid & 63) == 0) red[tid >> 6] = s;
    __syncthreads();
    s = red[0] + red[1] + red[2] + red[3];
    float inv = __fdividef(1.f, s);
    if (tid < 32) la[tid] = __expf(g_scores[b * TT + tt * 32 + tid] - m) * inv;
    __syncthreads();

    const float4* ep = (const float4*)(enc + ((size_t)b * TT + tt * 32) * ENCD) + tid;
    float ax = 0.f, ay = 0.f, az = 0.f, aw = 0.f;
#pragma unroll 8
    for (int t = 0; t < 32; t++) {
        float4 e = ep[(size_t)t * (ENCD / 4)];
        float w = la[t];
        ax = fmaf(w, e.x, ax); ay = fmaf(w, e.y, ay);
        az = fmaf(w, e.z, az); aw = fmaf(w, e.w, aw);
    }
    float4 r; r.x = ax; r.y = ay; r.z = az; r.w = aw;
    ((float4*)g_cp)[((size_t)tt * BB + b) * (ENCD / 4) + tid] = r;
}

// ---------------------------------------------------------------------------
// K3: ctx[b,d] = sum_tt g_cp[tt][b][d]  (coalesced 32-way reduce, 4 MB)
// ---------------------------------------------------------------------------
__global__ __launch_bounds__(256) void k_ctxsum() {
    int i = blockIdx.x * 256 + threadIdx.x;   // grid 128 -> 32768
    float a = 0.f;
#pragma unroll 8
    for (int tt = 0; tt < NTT; tt++) a += g_cp[tt * (BB * ENCD) + i];
    g_ctx[i] = a;
}

// ---------------------------------------------------------------------------
// K4: z partials. grid 544 = 16 jt x 34 kc (KCH=64; last chunk 16 rows).
// x staged in LDS for all 32 batches; weight loads batched 8-wide.
// ---------------------------------------------------------------------------
__global__ __launch_bounds__(256) void k_zmm(const float* __restrict__ pm,
                                             const float* __restrict__ h,
                                             const float* __restrict__ kern,
                                             const float* __restrict__ reck) {
    __shared__ float xs[KCH * 32];
    int jt = blockIdx.x & 15, kc = blockIdx.x >> 4;
    int k0 = kc * KCH;
    int kcount = min(KCH, KTOT - k0);   // 64 or 16, both divisible by 8
    int tid = threadIdx.x;
    for (int idx = tid; idx < kcount * 32; idx += 256) {
        int kk = idx >> 5, b = idx & 31;
        int k = k0 + kk;
        float v;
        if (k < MELD)             v = pm[b * MELD + k];
        else if (k < MELD + ENCD) v = g_ctx[b * ENCD + (k - MELD)];
        else                      v = h[b * DECD + (k - MELD - ENCD)];
        xs[idx] = v;
    }
    __syncthreads();
    int j = jt * 256 + tid;
    float acc[32];
#pragma unroll
    for (int b = 0; b < 32; b++) acc[b] = 0.f;
    for (int kk0 = 0; kk0 < kcount; kk0 += 8) {
        float w[8];
#pragma unroll
        for (int i = 0; i < 8; i++) {
            int k = k0 + kk0 + i;
            w[i] = (k < MELD + ENCD) ? kern[(size_t)k * NZ + j]
                                     : reck[(size_t)(k - MELD - ENCD) * NZ + j];
        }
#pragma unroll
        for (int i = 0; i < 8; i++) {
            const float* xr = xs + (kk0 + i) * 32;
#pragma unroll
            for (int b = 0; b < 32; b++) acc[b] = fmaf(xr[b], w[i], acc[b]);
        }
    }
#pragma unroll
    for (int b = 0; b < 32; b++) g_zp[((size_t)kc * BB + b) * NZ + j] = acc[b];
}

// ---------------------------------------------------------------------------
// K5: sum z partials + bias, gates -> h_new/c_new (fp32 out).
// grid 512 = 32 b x 16 jt (j-tile 64); kc-sum split 4-way across thread
// groups, LDS reduce. out: mel[0,2560) h[2560,35328) c[35328,68096)
// ---------------------------------------------------------------------------
__global__ __launch_bounds__(256) void k_gates(const float* __restrict__ bias,
                                               const float* __restrict__ c,
                                               float* __restrict__ out) {
    __shared__ float sacc[4][4][64];   // [grp][gate][jl]
    int b = blockIdx.x >> 4, jq = blockIdx.x & 15;
    int jl = threadIdx.x & 63, grp = threadIdx.x >> 6;
    int j = jq * 64 + jl;
    // kc ranges per group: 9,9,9,7
    int kc0 = grp * 9;
    int kc1 = min(kc0 + 9, KC);
    float zi = 0.f, zf = 0.f, zg = 0.f, zo = 0.f;
    for (int kc = kc0; kc < kc1; kc++) {
        const float* zp = g_zp + ((size_t)kc * BB + b) * NZ;
        zi += zp[j];
        zf += zp[1024 + j];
        zg += zp[2048 + j];
        zo += zp[3072 + j];
    }
    sacc[grp][0][jl] = zi; sacc[grp][1][jl] = zf;
    sacc[grp][2][jl] = zg; sacc[grp][3][jl] = zo;
    __syncthreads();
    if (grp == 0) {
        zi = sacc[0][0][jl] + sacc[1][0][jl] + sacc[2][0][jl] + sacc[3][0][jl] + bias[j];
        zf = sacc[0][1][jl] + sacc[1][1][jl] + sacc[2][1][jl] + sacc[3][1][jl] + bias[1024 + j];
        zg = sacc[0][2][jl] + sacc[1][2][jl] + sacc[2][2][jl] + sacc[3][2][jl] + bias[2048 + j];
        zo = sacc[0][3][jl] + sacc[1][3][jl] + sacc[2][3][jl] + sacc[3][3][jl] + bias[3072 + j];
        int idx = b * 1024 + j;
        float cn = sigmoid_fast(zf) * c[idx] + sigmoid_fast(zi) * tanh_fast(zg);
        float hn = sigmoid_fast(zo) * tanh_fast(cn);
        g_hn[idx] = hn;
        out[2560 + idx] = hn;
        out[35328 + idx] = cn;
    }
}

// ---------------------------------------------------------------------------
// K6: mel[b,m] = h_new[b,:] @ proj_w[:,m] + proj_b[m]
// grid 32; 160 active threads = 80 m x 2 d-halves, LDS combine.
// ---------------------------------------------------------------------------
__global__ __launch_bounds__(256) void k_proj(const float* __restrict__ pw,
                                              const float* __restrict__ pb,
                                              float* __restrict__ out) {
    __shared__ float lh[1024];
    __shared__ float pacc[2][MELD];
    int b = blockIdx.x, tid = threadIdx.x;
    for (int i = tid; i < 1024; i += 256) lh[i] = g_hn[b * 1024 + i];
    __syncthreads();
    int m = tid & 127;
    int g = tid >> 7;
    if (m < MELD) {
        float acc = 0.f;
        int d0 = g * 512;
#pragma unroll 8
        for (int d = d0; d < d0 + 512; d++) acc = fmaf(lh[d], pw[d * MELD + m], acc);
        pacc[g][m] = acc;
    }
    __syncthreads();
    if (tid < MELD) out[b * MELD + tid] = pacc[0][tid] + pacc[1][tid] + pb[tid];
}

extern "C" void kernel_launch(void* const* d_in, const int* in_sizes, int n_in,
                              void* d_out, int out_size, void* d_ws, size_t ws_size,
                              hipStream_t stream) {
    const float* pm   = (const float*)d_in[0];   // prev_mel_frame [32,80]
    const float* enc  = (const float*)d_in[1];   // encoder_outputs [32,1024,1024]
    const float* h    = (const float*)d_in[2];   // h [32,1024]
    const float* c    = (const float*)d_in[3];   // c [32,1024]
    const float* asc  = (const float*)d_in[4];   // attn_scale [1024]
    const float* kern = (const float*)d_in[5];   // kernel [1104,4096]
    const float* reck = (const float*)d_in[6];   // rec_kernel [1024,4096]
    const float* bias = (const float*)d_in[7];   // bias [4096]
    const float* pw   = (const float*)d_in[8];   // proj_w [1024,80]
    const float* pb   = (const float*)d_in[9];   // proj_b [80]
    float* out = (float*)d_out;                  // fp32: mel | h_new | c_new

    k_scores <<<8192, 256, 0, stream>>>(enc, h, asc);
    k_context<<<dim3(32, NTT), 256, 0, stream>>>(enc);
    k_ctxsum <<<128, 256, 0, stream>>>();
    k_zmm    <<<544, 256, 0, stream>>>(pm, h, kern, reck);
    k_gates  <<<512, 256, 0, stream>>>(bias, c, out);
    k_proj   <<<32, 256, 0, stream>>>(pw, pb, out);
}